// Round 5
// baseline (237.278 us; speedup 1.0000x reference)
//
#include <hip/hip_runtime.h>
#include <math.h>

#define B_ 128
#define G_ 16
#define A_ 8732
#define C_ 21
#define THR_ 0.5f
#define NEG_POS_ 3
#define VAR0_ 0.1f
#define VAR1_ 0.2f

#define BA_   (B_ * A_)              // 1,117,696 (divisible by 4)
#define NTH_  (BA_ / 4)              // 279,424 threads, 4 anchors each
#define NBLK_ ((NTH_ + 255) / 256)   // 1092 blocks

#define MTPB_ 768                    // match kernel threads (12 waves)
#define MNW_  (MTPB_ / 64)

struct Accum { float loss_loc; float loss_cls; int done; int pad; };

// ---------------------------------------------------------------------------
// K1: per-batch matching. One 768-thread block per batch. Block 0 also zeroes
// the accumulator (safe: K2's atomics only start after K1 fully completes).
// ---------------------------------------------------------------------------
__global__ __launch_bounds__(MTPB_) void k_match(
    const float* __restrict__ tboxes,   // B,G,4 (point form)
    const int*   __restrict__ tlabels,  // B,G
    const float* __restrict__ anchors,  // A,4 (center form)
    int*         __restrict__ match,    // B*A packed conf|gt<<8
    int*         __restrict__ num_pos,  // B
    Accum*                    acc)
{
    const int b    = blockIdx.x;
    const int tid  = threadIdx.x;
    const int lane = tid & 63;
    const int w    = tid >> 6;          // 0..11

    if (b == 0 && tid == 0) {
        acc->loss_loc = 0.f;
        acc->loss_cls = 0.f;
        acc->done     = 0;
    }

    __shared__ float         s_ov[A_];
    __shared__ unsigned char s_gi[A_];
    __shared__ float s_boxlds[G_ * 4];
    __shared__ int   s_lab[G_];
    __shared__ unsigned long long s_gb[MNW_ * G_];
    __shared__ int   s_forced[G_];
    __shared__ int   s_cnt[MNW_];

    if (tid < G_ * 4) s_boxlds[tid] = tboxes[b * G_ * 4 + tid];
    if (tid < G_)     s_lab[tid]    = tlabels[b * G_ + tid];
    __syncthreads();

    float bx0[G_], by0[G_], bx1[G_], by1[G_], bar[G_];
    #pragma unroll
    for (int g = 0; g < G_; ++g) {
        bx0[g] = s_boxlds[g * 4 + 0];
        by0[g] = s_boxlds[g * 4 + 1];
        bx1[g] = s_boxlds[g * 4 + 2];
        by1[g] = s_boxlds[g * 4 + 3];
        bar[g] = (bx1[g] - bx0[g]) * (by1[g] - by0[g]);
    }

    unsigned long long gb[G_];
    #pragma unroll
    for (int g = 0; g < G_; ++g) gb[g] = 0ull;

    for (int a = tid; a < A_; a += MTPB_) {
        float4 an = ((const float4*)anchors)[a];
        float ax0 = an.x - an.z * 0.5f, ay0 = an.y - an.w * 0.5f;
        float ax1 = an.x + an.z * 0.5f, ay1 = an.y + an.w * 0.5f;
        float area_b = (ax1 - ax0) * (ay1 - ay0);   // mirror reference arithmetic
        float bov = -1.f; int bg = 0;
        #pragma unroll
        for (int g = 0; g < G_; ++g) {
            float tlx = fmaxf(bx0[g], ax0);
            float tly = fmaxf(by0[g], ay0);
            float brx = fminf(bx1[g], ax1);
            float bry = fminf(by1[g], ay1);
            float wdt = fmaxf(brx - tlx, 0.f);
            float hgt = fmaxf(bry - tly, 0.f);
            float inter = wdt * hgt;
            float iou = inter / (bar[g] + area_b - inter);
            if (iou > bov) { bov = iou; bg = g; }            // first g wins on ties
            unsigned long long pk =
                ((unsigned long long)__float_as_uint(iou) << 32) |
                (unsigned)(~(unsigned)a);                    // max iou, min a on ties
            if (pk > gb[g]) gb[g] = pk;
        }
        s_ov[a] = bov;
        s_gi[a] = (unsigned char)bg;
    }

    #pragma unroll
    for (int g = 0; g < G_; ++g) {
        #pragma unroll
        for (int off = 32; off > 0; off >>= 1) {
            unsigned long long o = __shfl_down(gb[g], off);
            if (o > gb[g]) gb[g] = o;
        }
    }
    if (lane == 0) {
        #pragma unroll
        for (int g = 0; g < G_; ++g) s_gb[w * G_ + g] = gb[g];
    }
    __syncthreads();
    if (tid < G_) {
        unsigned long long m = 0ull;
        #pragma unroll
        for (int wv = 0; wv < MNW_; ++wv) {
            unsigned long long v = s_gb[wv * G_ + tid];
            if (v > m) m = v;
        }
        s_forced[tid] = (int)(~(unsigned)(m & 0xFFFFFFFFull));
    }
    __syncthreads();
    if (tid == 0) {
        for (int g = 0; g < G_; ++g) {      // ascending g, last write wins (ref loop)
            int a = s_forced[g];
            s_ov[a] = 1.0f;
            s_gi[a] = (unsigned char)g;
        }
    }
    __syncthreads();

    int cnt = 0;
    for (int a = tid; a < A_; a += MTPB_) {
        float ov = s_ov[a];
        int g = s_gi[a];
        int conf = (ov < THR_) ? 0 : (s_lab[g] + 1);
        match[b * A_ + a] = conf | (g << 8);
        cnt += (conf > 0);
    }
    #pragma unroll
    for (int off = 32; off > 0; off >>= 1) cnt += __shfl_down(cnt, off);
    if (lane == 0) s_cnt[w] = cnt;
    __syncthreads();
    if (tid == 0) {
        int t = 0;
        #pragma unroll
        for (int wv = 0; wv < MNW_; ++wv) t += s_cnt[wv];
        num_pos[b] = t;
    }
}

// ---------------------------------------------------------------------------
// K2: per-anchor loss — full grid (1092 blocks), no LDS staging, no barriers
// before the epilogue. 4 anchors/thread = 21 aligned independent float4 loads.
// Block partials go straight to the accumulator via device-scope atomics.
// ---------------------------------------------------------------------------
__global__ __launch_bounds__(256) void k_loss(
    const float* __restrict__ pred_off,   // B,A,4
    const float* __restrict__ pred_conf,  // B,A,C
    const float* __restrict__ tboxes,     // B,G,4
    const float* __restrict__ anchors,    // A,4
    const int*   __restrict__ match,      // flat BA
    float*       __restrict__ aux,        // flat BA
    Accum*                    acc)
{
    const int tid  = threadIdx.x;
    const int t    = blockIdx.x * 256 + tid;
    const int lane = tid & 63;
    const int w    = tid >> 6;

    __shared__ float s_lloc[4];
    __shared__ float s_pnll[4];

    float lloc = 0.f, pnll = 0.f;

    if (t < NTH_) {
        const float4* cp = (const float4*)pred_conf + (size_t)t * 21;
        float xx[84];
        #pragma unroll
        for (int k = 0; k < 21; ++k) {
            float4 v = cp[k];
            xx[4 * k + 0] = v.x; xx[4 * k + 1] = v.y;
            xx[4 * k + 2] = v.z; xx[4 * k + 3] = v.w;
        }
        int4 mk = ((const int4*)match)[t];
        int mkv[4]; mkv[0] = mk.x; mkv[1] = mk.y; mkv[2] = mk.z; mkv[3] = mk.w;
        float auxv[4];

        #pragma unroll
        for (int j = 0; j < 4; ++j) {
            const int base = 21 * j;
            float m = xx[base];
            #pragma unroll
            for (int c = 1; c < C_; ++c) m = fmaxf(m, xx[base + c]);
            float s = 0.f;
            #pragma unroll
            for (int c = 0; c < C_; ++c) s += __expf(xx[base + c] - m);
            float lse = m + __logf(s);

            int conf = mkv[j] & 0xff;
            int g    = mkv[j] >> 8;
            float xc = xx[base];
            #pragma unroll
            for (int c = 1; c < C_; ++c) xc = (conf == c) ? xx[base + c] : xc;
            float nll = lse - xc;
            bool pos = conf > 0;
            auxv[j] = pos ? 0.f : nll;

            if (pos) {
                pnll += nll;
                int i = t * 4 + j;          // flat anchor id
                int b = i / A_;
                int a = i - b * A_;
                float4 an = ((const float4*)anchors)[a];
                float4 bx = ((const float4*)tboxes)[b * G_ + g];
                float gcx = (bx.x + bx.z) * 0.5f, gcy = (bx.y + bx.w) * 0.5f;
                float gw = bx.z - bx.x, gh = bx.w - bx.y;
                float l0 = (gcx - an.x) / (an.z * VAR0_);
                float l1 = (gcy - an.y) / (an.w * VAR0_);
                float l2 = logf(gw / an.z) / VAR1_;
                float l3 = logf(gh / an.w) / VAR1_;
                float4 p = ((const float4*)pred_off)[i];
                float d, ad;
                d = p.x - l0; ad = fabsf(d); lloc += (ad < 1.f) ? 0.5f * d * d : ad - 0.5f;
                d = p.y - l1; ad = fabsf(d); lloc += (ad < 1.f) ? 0.5f * d * d : ad - 0.5f;
                d = p.z - l2; ad = fabsf(d); lloc += (ad < 1.f) ? 0.5f * d * d : ad - 0.5f;
                d = p.w - l3; ad = fabsf(d); lloc += (ad < 1.f) ? 0.5f * d * d : ad - 0.5f;
            }
        }
        ((float4*)aux)[t] = make_float4(auxv[0], auxv[1], auxv[2], auxv[3]);
    }

    #pragma unroll
    for (int off = 32; off > 0; off >>= 1) {
        lloc += __shfl_down(lloc, off);
        pnll += __shfl_down(pnll, off);
    }
    if (lane == 0) { s_lloc[w] = lloc; s_pnll[w] = pnll; }
    __syncthreads();
    if (tid == 0) {
        float L = s_lloc[0] + s_lloc[1] + s_lloc[2] + s_lloc[3];
        float P = s_pnll[0] + s_pnll[1] + s_pnll[2] + s_pnll[3];
        if (L != 0.f) atomicAdd(&acc->loss_loc, L);
        if (P != 0.f) atomicAdd(&acc->loss_cls, P);
    }
}

// ---------------------------------------------------------------------------
// K3: per-batch hard-negative mining + in-kernel finalize (last block).
// 256 threads; A values in 35 registers/thread; exact K-th largest via
// bitwise binary search; last-arriving block divides and writes out.
// ---------------------------------------------------------------------------
#define NPT_ 35   // ceil(8732/256)
__global__ __launch_bounds__(256) void k_select(
    const float* __restrict__ aux,
    const int*   __restrict__ num_pos,
    Accum*                    acc,
    float*       __restrict__ out)
{
    const int b    = blockIdx.x;
    const int tid  = threadIdx.x;
    const int lane = tid & 63;
    const int w    = tid >> 6;           // 0..3

    __shared__ int   s_c[2][4];
    __shared__ int   s_cf[4];
    __shared__ float s_sf[4];
    __shared__ int   s_last;

    unsigned u[NPT_];
    #pragma unroll
    for (int j = 0; j < NPT_; ++j) {
        int a = tid + j * 256;
        u[j] = (a < A_) ? __float_as_uint(aux[(size_t)b * A_ + a]) : 0u;
    }

    const int K = min(NEG_POS_ * num_pos[b], A_ - 1);

    unsigned lo = 0u, hi = 0x7f800000u;
    int it = 0;
    while (lo < hi) {
        unsigned mid = (lo + hi) >> 1;
        int c = 0;
        #pragma unroll
        for (int j = 0; j < NPT_; ++j) c += (u[j] > mid);
        #pragma unroll
        for (int off = 32; off > 0; off >>= 1) c += __shfl_down(c, off);
        if (lane == 0) s_c[it & 1][w] = c;
        __syncthreads();
        int total = s_c[it & 1][0] + s_c[it & 1][1] + s_c[it & 1][2] + s_c[it & 1][3];
        if (total >= K) lo = mid + 1; else hi = mid;
        ++it;
    }
    // lo == bit pattern of T = K-th largest value

    int c = 0; float sm = 0.f;
    #pragma unroll
    for (int j = 0; j < NPT_; ++j) {
        if (u[j] > lo) { c++; sm += __uint_as_float(u[j]); }
    }
    #pragma unroll
    for (int off = 32; off > 0; off >>= 1) {
        c  += __shfl_down(c, off);
        sm += __shfl_down(sm, off);
    }
    if (lane == 0) { s_cf[w] = c; s_sf[w] = sm; }
    __syncthreads();
    if (tid == 0) {
        int   ct = s_cf[0] + s_cf[1] + s_cf[2] + s_cf[3];
        float st = s_sf[0] + s_sf[1] + s_sf[2] + s_sf[3];
        float T = __uint_as_float(lo);
        atomicAdd(&acc->loss_cls, st + (float)(K - ct) * T);
        __threadfence();
        int prev = atomicAdd(&acc->done, 1);
        s_last = (prev == B_ - 1) ? 1 : 0;
    }
    __syncthreads();

    if (s_last) {
        // all other blocks' atomics are visible (their add -> fence -> done++)
        int n = (tid < B_) ? num_pos[tid] : 0;   // tid 0..127 -> waves 0,1
        #pragma unroll
        for (int off = 32; off > 0; off >>= 1) n += __shfl_down(n, off);
        if (lane == 0) s_cf[w] = n;
        __syncthreads();
        if (tid == 0) {
            float nt = (float)(s_cf[0] + s_cf[1]);
            float L  = atomicAdd(&acc->loss_loc, 0.f);   // L2-coherent read
            float Cc = atomicAdd(&acc->loss_cls, 0.f);
            out[0] = L / nt;
            out[1] = Cc / nt;
        }
    }
}

// ---------------------------------------------------------------------------
extern "C" void kernel_launch(void* const* d_in, const int* in_sizes, int n_in,
                              void* d_out, int out_size, void* d_ws, size_t ws_size,
                              hipStream_t stream) {
    const float* pred_off  = (const float*)d_in[0];  // B,A,4
    const float* pred_conf = (const float*)d_in[1];  // B,A,C
    const float* tboxes    = (const float*)d_in[2];  // B,G,4
    const int*   tlabels   = (const int*)  d_in[3];  // B,G
    const float* anchors   = (const float*)d_in[4];  // A,4
    float* out = (float*)d_out;

    char* ws = (char*)d_ws;
    int*   match_ws = (int*)ws;     ws += (size_t)BA_ * sizeof(int);
    float* aux_ws   = (float*)ws;   ws += (size_t)BA_ * sizeof(float);
    int*   npos_ws  = (int*)ws;     ws += (size_t)((B_ + 3) & ~3) * sizeof(int);
    Accum* acc      = (Accum*)ws;

    k_match<<<B_, MTPB_, 0, stream>>>(tboxes, tlabels, anchors, match_ws, npos_ws, acc);
    k_loss<<<NBLK_, 256, 0, stream>>>(pred_off, pred_conf, tboxes, anchors,
                                      match_ws, aux_ws, acc);
    k_select<<<B_, 256, 0, stream>>>(aux_ws, npos_ws, acc, out);
}